// Round 5
// baseline (465.673 us; speedup 1.0000x reference)
//
#include <hip/hip_runtime.h>
#include <hip/hip_bf16.h>
#include <math.h>

#define T_LEN 4096
#define BATCH 16

// ---------------------------------------------------------------------------
// k_gcn: adapter + node projections + A_HAT propagation + relu + node-mean.
// thread = (d=lane, 4 timesteps); per-c fragment read is one wave-uniform
// ds_read_b128 (broadcast) feeding 4 FMAs with register weights.
// Output hp [B][64][T] channel-major.
// ---------------------------------------------------------------------------
__global__ __launch_bounds__(256) void k_gcn(
    const float* __restrict__ x,      // [B][T][218]
    const float* __restrict__ gcn_w,  // [18][64]
    float* __restrict__ hp)           // [B][64][T]
{
    __shared__ float xt[218 * 20];    // [c][16 t], stride 20 (16B-aligned)

    const int b   = blockIdx.y;
    const int t0  = blockIdx.x * 16;
    const int tid = threadIdx.x;

    const float* xb = x + ((long)b * T_LEN + t0) * 218;
    #pragma unroll 1
    for (int i = tid; i < 16 * 218; i += 256) {
        const int t = i / 218;
        const int c = i - 218 * t;
        xt[c * 20 + t] = xb[i];
    }
    __syncthreads();

    const int d  = tid & 63;
    const int w  = tid >> 6;
    const int tb = w * 4;

    float wr[18];
    #pragma unroll
    for (int c = 0; c < 18; ++c) wr[c] = gcn_w[c * 64 + d];

    const float cP = 1.0f / 6.0f;
    const float cS = 0.23570226039551584f;   // 1/sqrt(18)
    const float c3 = 1.0f / 3.0f;
    const float cT = 0.4082482904638631f;    // 1/sqrt(6)
    const float cH = 0.5f;

    float h0[4] = {0.f, 0.f, 0.f, 0.f};
    #pragma unroll
    for (int c = 0; c < 18; ++c) {
        float xv[4];
        *(float4*)xv = *(const float4*)(&xt[c * 20 + tb]);
        #pragma unroll
        for (int ti = 0; ti < 4; ++ti) h0[ti] = fmaf(wr[c], xv[ti], h0[ti]);
    }

    float pool[4] = {0.f, 0.f, 0.f, 0.f};
    float star[4] = {0.f, 0.f, 0.f, 0.f};

    #pragma unroll 1
    for (int f = 0; f < 5; ++f) {
        float hf[4][4];
        #pragma unroll
        for (int n = 0; n < 4; ++n) {
            #pragma unroll
            for (int ti = 0; ti < 4; ++ti) hf[n][ti] = 0.f;
            const int cb = 18 + 10 * (4 * f + n);
            #pragma unroll
            for (int c = 0; c < 10; ++c) {
                float xv[4];
                *(float4*)xv = *(const float4*)(&xt[(cb + c) * 20 + tb]);
                #pragma unroll
                for (int ti = 0; ti < 4; ++ti)
                    hf[n][ti] = fmaf(wr[c], xv[ti], hf[n][ti]);
            }
        }
        #pragma unroll
        for (int ti = 0; ti < 4; ++ti) {
            const float ha = hf[0][ti], h2 = hf[1][ti];
            const float h3 = hf[2][ti], he = hf[3][ti];
            star[ti] += ha;
            const float pa = fmaf(cS, h0[ti], c3 * (ha + h2));
            const float pb = c3 * (ha + h2 + h3);
            const float pc = fmaf(cT, he, c3 * (h2 + h3));
            const float pe = fmaf(cT, h3, cH * he);
            pool[ti] += fmaxf(pa, 0.f) + fmaxf(pb, 0.f) +
                        fmaxf(pc, 0.f) + fmaxf(pe, 0.f);
        }
    }

    __syncthreads();
    #pragma unroll
    for (int ti = 0; ti < 4; ++ti) {
        const float p0 = fmaf(cP, h0[ti], cS * star[ti]);
        xt[d * 20 + tb + ti] = (pool[ti] + fmaxf(p0, 0.f)) * (1.0f / 21.0f);
    }
    __syncthreads();

    float* hpb = hp + (long)b * 64 * T_LEN + t0;
    #pragma unroll 1
    for (int i = tid; i < 64 * 16; i += 256) {
        const int dd = i >> 4;
        const int t  = i & 15;
        hpb[(long)dd * T_LEN + t] = xt[dd * 20 + t];
    }
}

// ---------------------------------------------------------------------------
// k_mstcn: one full MSTCN block, fused (convs + relu + 1x1 conv_out; FINAL
// adds dense 64->32 + tanh + mean).  t-tile = 32 -> grid 2048 blocks
// (8/CU-worth: scheduler backfill when short conv waves retire).
// Thread layout conv: rotated jg (4 j) x tt (2 t); acc[4][2].
// LDS: input tile [64c][64w + pad4] = 17.4 KB; h staged aliased after a
// barrier.  Window reads are aligned ds_read_b64, conflict-free.
// ---------------------------------------------------------------------------
template <bool FINAL>
__global__ __launch_bounds__(256) void k_mstcn(
    const float* __restrict__ in,   // [B][64][T]
    const float* __restrict__ ws, const float* __restrict__ bs,
    const float* __restrict__ wm, const float* __restrict__ bm,
    const float* __restrict__ wl, const float* __restrict__ bl,
    const float* __restrict__ wo, const float* __restrict__ bo,
    float* __restrict__ out,        // [B][64][T]  (FINAL=false)
    const float* __restrict__ wd,   // [64][32]    (FINAL=true)
    const float* __restrict__ bd,   // [32]
    float* __restrict__ outp)       // [B][32]     (FINAL=true)
{
    __shared__ float smem[64 * 68];   // tile [c][64], stride 68; aliased for h

    const int b   = blockIdx.y;
    const int t0  = blockIdx.x * 32;
    const int tid = threadIdx.x;
    const int jl  = ((tid >> 4) + (blockIdx.x << 2)) & 15;  // rotated j-group
    const int tt  = tid & 15;                                // t-group of 2
    const int j0  = jl * 4;

    // ---- stage input window [t0-32, t0+32) as [c][64], stride 68 ----
    const float* inb = in + (long)b * 64 * T_LEN;
    #pragma unroll 1
    for (int i = tid; i < 64 * 16; i += 256) {
        const int c = i >> 4;
        const int q = i & 15;
        const int t = t0 - 32 + q * 4;
        float4 v = make_float4(0.f, 0.f, 0.f, 0.f);
        if (t >= 0) v = *(const float4*)(inb + (long)c * T_LEN + t);
        *(float4*)(&smem[c * 68 + q * 4]) = v;
    }
    __syncthreads();

    float acc[4][2];

    if (jl < 4) {
        // conv_s: k=3, d=1 (concat 0..15)
        #pragma unroll
        for (int ji = 0; ji < 4; ++ji)
            acc[ji][0] = acc[ji][1] = bs[j0 + ji];
        const float* wp = ws + j0;
        float w[3][4];
        #pragma unroll
        for (int k = 0; k < 3; ++k) *(float4*)w[k] = *(const float4*)(wp + k * 1024);
        #pragma unroll 1
        for (int c = 0; c < 64; ++c) {
            const float* row = &smem[c * 68 + 32 + tt * 2];
            const float2 A = *(const float2*)(row - 2);
            const float2 B = *(const float2*)(row);
            const float vx[3] = {A.x, A.y, B.x};
            const float vy[3] = {A.y, B.x, B.y};
            const float* wn = wp + (c < 63 ? (c + 1) * 16 : 63 * 16);
            #pragma unroll
            for (int k = 0; k < 3; ++k) {
                #pragma unroll
                for (int ji = 0; ji < 4; ++ji) {
                    acc[ji][0] = fmaf(w[k][ji], vx[k], acc[ji][0]);
                    acc[ji][1] = fmaf(w[k][ji], vy[k], acc[ji][1]);
                }
                *(float4*)w[k] = *(const float4*)(wn + k * 1024);
            }
        }
    } else if (jl < 8) {
        // conv_m: k=5, d=2 (concat 16..31)
        #pragma unroll
        for (int ji = 0; ji < 4; ++ji)
            acc[ji][0] = acc[ji][1] = bm[j0 - 16 + ji];
        const float* wp = wm + (j0 - 16);
        float w[5][4];
        #pragma unroll
        for (int k = 0; k < 5; ++k) *(float4*)w[k] = *(const float4*)(wp + k * 1024);
        #pragma unroll 1
        for (int c = 0; c < 64; ++c) {
            const float* row = &smem[c * 68 + 32 + tt * 2];
            float2 M[5];
            #pragma unroll
            for (int k = 0; k < 5; ++k) M[k] = *(const float2*)(row - 8 + 2 * k);
            const float* wn = wp + (c < 63 ? (c + 1) * 16 : 63 * 16);
            #pragma unroll
            for (int k = 0; k < 5; ++k) {
                #pragma unroll
                for (int ji = 0; ji < 4; ++ji) {
                    acc[ji][0] = fmaf(w[k][ji], M[k].x, acc[ji][0]);
                    acc[ji][1] = fmaf(w[k][ji], M[k].y, acc[ji][1]);
                }
                *(float4*)w[k] = *(const float4*)(wn + k * 1024);
            }
        }
    } else {
        // conv_l: k=9, d=4 (concat 32..63)
        #pragma unroll
        for (int ji = 0; ji < 4; ++ji)
            acc[ji][0] = acc[ji][1] = bl[j0 - 32 + ji];
        const float* wp = wl + (j0 - 32);
        float w[9][4];
        #pragma unroll
        for (int k = 0; k < 9; ++k) *(float4*)w[k] = *(const float4*)(wp + k * 2048);
        #pragma unroll 1
        for (int c = 0; c < 64; ++c) {
            const float* row = &smem[c * 68 + 32 + tt * 2];
            float2 L[9];
            #pragma unroll
            for (int k = 0; k < 9; ++k) L[k] = *(const float2*)(row - 32 + 4 * k);
            const float* wn = wp + (c < 63 ? (c + 1) * 32 : 63 * 32);
            #pragma unroll
            for (int k = 0; k < 9; ++k) {
                #pragma unroll
                for (int ji = 0; ji < 4; ++ji) {
                    acc[ji][0] = fmaf(w[k][ji], L[k].x, acc[ji][0]);
                    acc[ji][1] = fmaf(w[k][ji], L[k].y, acc[ji][1]);
                }
                *(float4*)w[k] = *(const float4*)(wn + k * 2048);
            }
        }
    }

    // relu; then re-stage h into LDS (aliased onto the tile -> barrier first)
    __syncthreads();
    #pragma unroll
    for (int ji = 0; ji < 4; ++ji) {
        float2 v = make_float2(fmaxf(acc[ji][0], 0.f), fmaxf(acc[ji][1], 0.f));
        *(float2*)(&smem[(j0 + ji) * 36 + tt * 2]) = v;
    }
    __syncthreads();

    // ---- conv_out 64->64 (no relu): thread = 4 d x 2 t, 4-deep rotation ----
    const int dg = tid >> 4;
    const int d0 = dg * 4;
    float o[4][2];
    {
        float bv[4];
        *(float4*)bv = *(const float4*)(bo + d0);
        #pragma unroll
        for (int di = 0; di < 4; ++di) o[di][0] = o[di][1] = bv[di];
    }
    float wob[4][4];
    float2 hb2[4];
    #pragma unroll
    for (int p = 0; p < 4; ++p) {
        *(float4*)wob[p] = *(const float4*)(wo + p * 64 + d0);
        hb2[p] = *(const float2*)(&smem[p * 36 + tt * 2]);
    }
    #pragma unroll 1
    for (int j4 = 0; j4 < 16; ++j4) {
        #pragma unroll
        for (int p = 0; p < 4; ++p) {
            const int j = j4 * 4 + p;
            #pragma unroll
            for (int di = 0; di < 4; ++di) {
                o[di][0] = fmaf(wob[p][di], hb2[p].x, o[di][0]);
                o[di][1] = fmaf(wob[p][di], hb2[p].y, o[di][1]);
            }
            const int jn = (j + 4 < 64) ? j + 4 : j;
            *(float4*)wob[p] = *(const float4*)(wo + jn * 64 + d0);
            hb2[p] = *(const float2*)(&smem[jn * 36 + tt * 2]);
        }
    }

    if (!FINAL) {
        float* ob = out + (long)b * 64 * T_LEN + t0 + tt * 2;
        #pragma unroll
        for (int di = 0; di < 4; ++di)
            *(float2*)(ob + (long)(d0 + di) * T_LEN) = make_float2(o[di][0], o[di][1]);
    } else {
        // ---- fused head: dense 64->32 + tanh + mean over T ----
        __syncthreads();
        #pragma unroll
        for (int di = 0; di < 4; ++di)
            *(float2*)(&smem[(d0 + di) * 36 + tt * 2]) = make_float2(o[di][0], o[di][1]);
        __syncthreads();

        const int lane = tid & 63;
        const int w    = tid >> 6;
        const int tl   = lane & 31;             // timestep within tile
        const int e0   = w * 8 + (lane >> 5) * 4;  // 4 output features

        float f[4];
        *(float4*)f = *(const float4*)(bd + e0);
        #pragma unroll 4
        for (int d = 0; d < 64; ++d) {
            const float v = smem[d * 36 + tl];
            float wv[4];
            *(float4*)wv = *(const float4*)(wd + d * 32 + e0);
            #pragma unroll
            for (int e = 0; e < 4; ++e) f[e] = fmaf(wv[e], v, f[e]);
        }
        #pragma unroll
        for (int e = 0; e < 4; ++e) {
            float v = tanhf(f[e]) * (1.0f / (float)T_LEN);
            v += __shfl_down(v, 16, 32);
            v += __shfl_down(v, 8, 32);
            v += __shfl_down(v, 4, 32);
            v += __shfl_down(v, 2, 32);
            v += __shfl_down(v, 1, 32);
            if (tl == 0) atomicAdd(&outp[b * 32 + e0 + e], v);
        }
    }
}

extern "C" void kernel_launch(void* const* d_in, const int* in_sizes, int n_in,
                              void* d_out, int out_size, void* d_ws, size_t ws_size,
                              hipStream_t stream) {
    const float* x     = (const float*)d_in[0];
    const float* gcn_w = (const float*)d_in[1];
    const float* wd    = (const float*)d_in[2];
    const float* bd    = (const float*)d_in[3];
    const float* t1_ws = (const float*)d_in[4];
    const float* t1_bs = (const float*)d_in[5];
    const float* t1_wm = (const float*)d_in[6];
    const float* t1_bm = (const float*)d_in[7];
    const float* t1_wl = (const float*)d_in[8];
    const float* t1_bl = (const float*)d_in[9];
    const float* t1_wo = (const float*)d_in[10];
    const float* t1_bo = (const float*)d_in[11];
    const float* t2_ws = (const float*)d_in[12];
    const float* t2_bs = (const float*)d_in[13];
    const float* t2_wm = (const float*)d_in[14];
    const float* t2_bm = (const float*)d_in[15];
    const float* t2_wl = (const float*)d_in[16];
    const float* t2_bl = (const float*)d_in[17];
    const float* t2_wo = (const float*)d_in[18];
    const float* t2_bo = (const float*)d_in[19];

    float* b0 = (float*)d_ws;                          // [16][64][4096]
    float* b1 = b0 + (size_t)BATCH * 64 * T_LEN;       // [16][64][4096]

    hipMemsetAsync(d_out, 0, (size_t)out_size * sizeof(float), stream);

    k_gcn<<<dim3(T_LEN / 16, BATCH), 256, 0, stream>>>(x, gcn_w, b0);

    k_mstcn<false><<<dim3(T_LEN / 32, BATCH), 256, 0, stream>>>(
        b0, t1_ws, t1_bs, t1_wm, t1_bm, t1_wl, t1_bl, t1_wo, t1_bo,
        b1, nullptr, nullptr, nullptr);

    k_mstcn<true><<<dim3(T_LEN / 32, BATCH), 256, 0, stream>>>(
        b1, t2_ws, t2_bs, t2_wm, t2_bm, t2_wl, t2_bl, t2_wo, t2_bo,
        nullptr, wd, bd, (float*)d_out);
}

// Round 6
// 389.404 us; speedup vs baseline: 1.1959x; 1.1959x over previous
//
#include <hip/hip_runtime.h>
#include <hip/hip_bf16.h>
#include <math.h>

#define T_LEN 4096
#define BATCH 16

// ---------------------------------------------------------------------------
// k_gcn: adapter + node projections + A_HAT propagation + relu + node-mean.
// (unchanged from R5 — measured this round via top-5 visibility)
// ---------------------------------------------------------------------------
__global__ __launch_bounds__(256) void k_gcn(
    const float* __restrict__ x,      // [B][T][218]
    const float* __restrict__ gcn_w,  // [18][64]
    float* __restrict__ hp)           // [B][64][T]
{
    __shared__ float xt[218 * 20];    // [c][16 t], stride 20

    const int b   = blockIdx.y;
    const int t0  = blockIdx.x * 16;
    const int tid = threadIdx.x;

    const float* xb = x + ((long)b * T_LEN + t0) * 218;
    #pragma unroll 1
    for (int i = tid; i < 16 * 218; i += 256) {
        const int t = i / 218;
        const int c = i - 218 * t;
        xt[c * 20 + t] = xb[i];
    }
    __syncthreads();

    const int d  = tid & 63;
    const int w  = tid >> 6;
    const int tb = w * 4;

    float wr[18];
    #pragma unroll
    for (int c = 0; c < 18; ++c) wr[c] = gcn_w[c * 64 + d];

    const float cP = 1.0f / 6.0f;
    const float cS = 0.23570226039551584f;   // 1/sqrt(18)
    const float c3 = 1.0f / 3.0f;
    const float cT = 0.4082482904638631f;    // 1/sqrt(6)
    const float cH = 0.5f;

    float h0[4] = {0.f, 0.f, 0.f, 0.f};
    #pragma unroll
    for (int c = 0; c < 18; ++c) {
        float xv[4];
        *(float4*)xv = *(const float4*)(&xt[c * 20 + tb]);
        #pragma unroll
        for (int ti = 0; ti < 4; ++ti) h0[ti] = fmaf(wr[c], xv[ti], h0[ti]);
    }

    float pool[4] = {0.f, 0.f, 0.f, 0.f};
    float star[4] = {0.f, 0.f, 0.f, 0.f};

    #pragma unroll 1
    for (int f = 0; f < 5; ++f) {
        float hf[4][4];
        #pragma unroll
        for (int n = 0; n < 4; ++n) {
            #pragma unroll
            for (int ti = 0; ti < 4; ++ti) hf[n][ti] = 0.f;
            const int cb = 18 + 10 * (4 * f + n);
            #pragma unroll
            for (int c = 0; c < 10; ++c) {
                float xv[4];
                *(float4*)xv = *(const float4*)(&xt[(cb + c) * 20 + tb]);
                #pragma unroll
                for (int ti = 0; ti < 4; ++ti)
                    hf[n][ti] = fmaf(wr[c], xv[ti], hf[n][ti]);
            }
        }
        #pragma unroll
        for (int ti = 0; ti < 4; ++ti) {
            const float ha = hf[0][ti], h2 = hf[1][ti];
            const float h3 = hf[2][ti], he = hf[3][ti];
            star[ti] += ha;
            const float pa = fmaf(cS, h0[ti], c3 * (ha + h2));
            const float pb = c3 * (ha + h2 + h3);
            const float pc = fmaf(cT, he, c3 * (h2 + h3));
            const float pe = fmaf(cT, h3, cH * he);
            pool[ti] += fmaxf(pa, 0.f) + fmaxf(pb, 0.f) +
                        fmaxf(pc, 0.f) + fmaxf(pe, 0.f);
        }
    }

    __syncthreads();
    #pragma unroll
    for (int ti = 0; ti < 4; ++ti) {
        const float p0 = fmaf(cP, h0[ti], cS * star[ti]);
        xt[d * 20 + tb + ti] = (pool[ti] + fmaxf(p0, 0.f)) * (1.0f / 21.0f);
    }
    __syncthreads();

    float* hpb = hp + (long)b * 64 * T_LEN + t0;
    #pragma unroll 1
    for (int i = tid; i < 64 * 16; i += 256) {
        const int dd = i >> 4;
        const int t  = i & 15;
        hpb[(long)dd * T_LEN + t] = xt[dd * 20 + t];
    }
}

// ---------------------------------------------------------------------------
// k_mstcn: full MSTCN fused, t-tile 64, grid 1024.  Both operand streams
// software-pipelined: conv_s/conv_m ping-pong window+weights across c+=2;
// conv_l rotates window and weight float4s per-tap (~256 cyc cover each).
// Rotated class->wave mapping balances SIMDs.  h never leaves LDS.
// ---------------------------------------------------------------------------
template <bool FINAL>
__global__ __launch_bounds__(256) void k_mstcn(
    const float* __restrict__ in,   // [B][64][T]
    const float* __restrict__ ws, const float* __restrict__ bs,
    const float* __restrict__ wm, const float* __restrict__ bm,
    const float* __restrict__ wl, const float* __restrict__ bl,
    const float* __restrict__ wo, const float* __restrict__ bo,
    float* __restrict__ out,        // [B][64][T]  (FINAL=false)
    const float* __restrict__ wd,   // [64][32]    (FINAL=true)
    const float* __restrict__ bd,   // [32]
    float* __restrict__ outp)       // [B][32]     (FINAL=true)
{
    __shared__ float smem[64 * 100]; // tile [c][96] stride 100; aliased for h

    const int b   = blockIdx.y;
    const int t0  = blockIdx.x * 64;
    const int tid = threadIdx.x;
    const int jl  = ((tid >> 4) + (blockIdx.x << 2)) & 15;  // rotated class map
    const int tt  = tid & 15;
    const int j0  = jl * 4;

    // ---- stage input window [t0-32, t0+64) as [c][96], stride 100 ----
    const float* inb = in + (long)b * 64 * T_LEN;
    #pragma unroll 1
    for (int i = tid; i < 64 * 24; i += 256) {
        const int c = i / 24;
        const int q = i - c * 24;
        const int t = t0 - 32 + q * 4;
        float4 v = make_float4(0.f, 0.f, 0.f, 0.f);
        if (t >= 0) v = *(const float4*)(inb + (long)c * T_LEN + t);
        *(float4*)(&smem[c * 100 + q * 4]) = v;
    }
    __syncthreads();

    float acc[4][4];

    if (jl < 4) {
        // ---- conv_s: k=3, d=1 (concat 0..15), c+=2 ping-pong ----
        #pragma unroll
        for (int ji = 0; ji < 4; ++ji) {
            const float bv = bs[j0 + ji];
            #pragma unroll
            for (int ti = 0; ti < 4; ++ti) acc[ji][ti] = bv;
        }
        const float* wp = ws + j0;
        float wA[3][4], wB[3][4], winA[8], winB[8];
        {
            const float4* r = (const float4*)(&smem[0]);
            *(float4*)(&winA[0]) = r[tt + 7];
            *(float4*)(&winA[4]) = r[tt + 8];
            #pragma unroll
            for (int k = 0; k < 3; ++k) *(float4*)wA[k] = *(const float4*)(wp + k * 1024);
        }
        #pragma unroll 1
        for (int c = 0; c < 64; c += 2) {
            {   // prefetch c+1
                const float4* r = (const float4*)(&smem[(c + 1) * 100]);
                *(float4*)(&winB[0]) = r[tt + 7];
                *(float4*)(&winB[4]) = r[tt + 8];
                const float* w1 = wp + (c + 1) * 16;
                #pragma unroll
                for (int k = 0; k < 3; ++k) *(float4*)wB[k] = *(const float4*)(w1 + k * 1024);
            }
            #pragma unroll
            for (int k = 0; k < 3; ++k) {
                const int off = 2 - k;
                #pragma unroll
                for (int ti = 0; ti < 4; ++ti) {
                    const float v = winA[4 + ti - off];
                    #pragma unroll
                    for (int ji = 0; ji < 4; ++ji)
                        acc[ji][ti] = fmaf(wA[k][ji], v, acc[ji][ti]);
                }
            }
            {   // prefetch c+2
                const int c2 = (c + 2 < 64) ? c + 2 : 62;
                const float4* r = (const float4*)(&smem[c2 * 100]);
                *(float4*)(&winA[0]) = r[tt + 7];
                *(float4*)(&winA[4]) = r[tt + 8];
                const float* w2 = wp + c2 * 16;
                #pragma unroll
                for (int k = 0; k < 3; ++k) *(float4*)wA[k] = *(const float4*)(w2 + k * 1024);
            }
            #pragma unroll
            for (int k = 0; k < 3; ++k) {
                const int off = 2 - k;
                #pragma unroll
                for (int ti = 0; ti < 4; ++ti) {
                    const float v = winB[4 + ti - off];
                    #pragma unroll
                    for (int ji = 0; ji < 4; ++ji)
                        acc[ji][ti] = fmaf(wB[k][ji], v, acc[ji][ti]);
                }
            }
        }
    } else if (jl < 8) {
        // ---- conv_m: k=5, d=2 (concat 16..31), c+=2 ping-pong ----
        #pragma unroll
        for (int ji = 0; ji < 4; ++ji) {
            const float bv = bm[j0 - 16 + ji];
            #pragma unroll
            for (int ti = 0; ti < 4; ++ti) acc[ji][ti] = bv;
        }
        const float* wp = wm + (j0 - 16);
        float wA[5][4], wB[5][4], winA[12], winB[12];
        {
            const float4* r = (const float4*)(&smem[0]);
            #pragma unroll
            for (int m = 0; m < 3; ++m) *(float4*)(&winA[4 * m]) = r[tt + 6 + m];
            #pragma unroll
            for (int k = 0; k < 5; ++k) *(float4*)wA[k] = *(const float4*)(wp + k * 1024);
        }
        #pragma unroll 1
        for (int c = 0; c < 64; c += 2) {
            {   // prefetch c+1
                const float4* r = (const float4*)(&smem[(c + 1) * 100]);
                #pragma unroll
                for (int m = 0; m < 3; ++m) *(float4*)(&winB[4 * m]) = r[tt + 6 + m];
                const float* w1 = wp + (c + 1) * 16;
                #pragma unroll
                for (int k = 0; k < 5; ++k) *(float4*)wB[k] = *(const float4*)(w1 + k * 1024);
            }
            #pragma unroll
            for (int k = 0; k < 5; ++k) {
                #pragma unroll
                for (int ti = 0; ti < 4; ++ti) {
                    const float v = winA[ti + 2 * k];
                    #pragma unroll
                    for (int ji = 0; ji < 4; ++ji)
                        acc[ji][ti] = fmaf(wA[k][ji], v, acc[ji][ti]);
                }
            }
            {   // prefetch c+2
                const int c2 = (c + 2 < 64) ? c + 2 : 62;
                const float4* r = (const float4*)(&smem[c2 * 100]);
                #pragma unroll
                for (int m = 0; m < 3; ++m) *(float4*)(&winA[4 * m]) = r[tt + 6 + m];
                const float* w2 = wp + c2 * 16;
                #pragma unroll
                for (int k = 0; k < 5; ++k) *(float4*)wA[k] = *(const float4*)(w2 + k * 1024);
            }
            #pragma unroll
            for (int k = 0; k < 5; ++k) {
                #pragma unroll
                for (int ti = 0; ti < 4; ++ti) {
                    const float v = winB[ti + 2 * k];
                    #pragma unroll
                    for (int ji = 0; ji < 4; ++ji)
                        acc[ji][ti] = fmaf(wB[k][ji], v, acc[ji][ti]);
                }
            }
        }
    } else {
        // ---- conv_l: k=9, d=4 (concat 32..63), per-tap rotation ----
        #pragma unroll
        for (int ji = 0; ji < 4; ++ji) {
            const float bv = bl[j0 - 32 + ji];
            #pragma unroll
            for (int ti = 0; ti < 4; ++ti) acc[ji][ti] = bv;
        }
        const float* wp = wl + (j0 - 32);
        float w[9][4], W[9][4];
        {
            const float4* r = (const float4*)(&smem[0]);
            #pragma unroll
            for (int k = 0; k < 9; ++k) {
                *(float4*)w[k] = *(const float4*)(wp + k * 2048);
                *(float4*)W[k] = r[tt + k];
            }
        }
        #pragma unroll 1
        for (int c = 0; c < 64; ++c) {
            const int cn = (c + 1 < 64) ? c + 1 : 63;
            const float4* rn = (const float4*)(&smem[cn * 100]);
            const float* wn = wp + cn * 32;
            #pragma unroll
            for (int k = 0; k < 9; ++k) {
                #pragma unroll
                for (int ti = 0; ti < 4; ++ti) {
                    const float v = W[k][ti];
                    #pragma unroll
                    for (int ji = 0; ji < 4; ++ji)
                        acc[ji][ti] = fmaf(w[k][ji], v, acc[ji][ti]);
                }
                *(float4*)W[k] = rn[tt + k];                     // window c+1
                *(float4*)w[k] = *(const float4*)(wn + k * 2048); // weights c+1
            }
        }
    }

    // relu; re-stage h into LDS (aliased onto the tile)
    __syncthreads();
    #pragma unroll
    for (int ji = 0; ji < 4; ++ji)
        *(float4*)(&smem[(j0 + ji) * 68 + tt * 4]) =
            make_float4(fmaxf(acc[ji][0], 0.f), fmaxf(acc[ji][1], 0.f),
                        fmaxf(acc[ji][2], 0.f), fmaxf(acc[ji][3], 0.f));
    __syncthreads();

    // ---- conv_out 64->64 (no relu): thread = 4 d x 4 t, 4-deep rotation ----
    const int dg = tid >> 4;
    const int d0 = dg * 4;
    float o[4][4];
    {
        float bv[4];
        *(float4*)bv = *(const float4*)(bo + d0);
        #pragma unroll
        for (int di = 0; di < 4; ++di)
            #pragma unroll
            for (int ti = 0; ti < 4; ++ti) o[di][ti] = bv[di];
    }
    float wob[4][4], hv4[4][4];
    #pragma unroll
    for (int p = 0; p < 4; ++p) {
        *(float4*)wob[p] = *(const float4*)(wo + p * 64 + d0);
        *(float4*)hv4[p] = *(const float4*)(&smem[p * 68 + tt * 4]);
    }
    #pragma unroll 1
    for (int j4 = 0; j4 < 16; ++j4) {
        #pragma unroll
        for (int p = 0; p < 4; ++p) {
            const int j = j4 * 4 + p;
            #pragma unroll
            for (int di = 0; di < 4; ++di)
                #pragma unroll
                for (int ti = 0; ti < 4; ++ti)
                    o[di][ti] = fmaf(wob[p][di], hv4[p][ti], o[di][ti]);
            const int jn = (j + 4 < 64) ? j + 4 : j;
            *(float4*)wob[p] = *(const float4*)(wo + jn * 64 + d0);
            *(float4*)hv4[p] = *(const float4*)(&smem[jn * 68 + tt * 4]);
        }
    }

    if (!FINAL) {
        float* ob = out + (long)b * 64 * T_LEN + t0 + tt * 4;
        #pragma unroll
        for (int di = 0; di < 4; ++di)
            *(float4*)(ob + (long)(d0 + di) * T_LEN) =
                make_float4(o[di][0], o[di][1], o[di][2], o[di][3]);
    } else {
        // ---- fused head: dense 64->32 + tanh + mean over T ----
        __syncthreads();
        #pragma unroll
        for (int di = 0; di < 4; ++di)
            *(float4*)(&smem[(d0 + di) * 68 + tt * 4]) =
                make_float4(o[di][0], o[di][1], o[di][2], o[di][3]);
        __syncthreads();

        const int tl = tid & 63;
        const int wv = tid >> 6;
        const int e0 = wv * 8;
        float f[8];
        *(float4*)(&f[0]) = *(const float4*)(bd + e0);
        *(float4*)(&f[4]) = *(const float4*)(bd + e0 + 4);

        float wdb[4][8], hb[4];
        #pragma unroll
        for (int p = 0; p < 4; ++p) {
            *(float4*)(&wdb[p][0]) = *(const float4*)(wd + p * 32 + e0);
            *(float4*)(&wdb[p][4]) = *(const float4*)(wd + p * 32 + e0 + 4);
            hb[p] = smem[p * 68 + tl];
        }
        #pragma unroll 1
        for (int d4 = 0; d4 < 16; ++d4) {
            #pragma unroll
            for (int p = 0; p < 4; ++p) {
                const int d = d4 * 4 + p;
                const float v = hb[p];
                #pragma unroll
                for (int e = 0; e < 8; ++e) f[e] = fmaf(wdb[p][e], v, f[e]);
                const int dn = (d + 4 < 64) ? d + 4 : d;
                *(float4*)(&wdb[p][0]) = *(const float4*)(wd + dn * 32 + e0);
                *(float4*)(&wdb[p][4]) = *(const float4*)(wd + dn * 32 + e0 + 4);
                hb[p] = smem[dn * 68 + tl];
            }
        }

        #pragma unroll
        for (int e = 0; e < 8; ++e) {
            float v = tanhf(f[e]) * (1.0f / (float)T_LEN);
            v += __shfl_down(v, 32);
            v += __shfl_down(v, 16);
            v += __shfl_down(v, 8);
            v += __shfl_down(v, 4);
            v += __shfl_down(v, 2);
            v += __shfl_down(v, 1);
            if (tl == 0) atomicAdd(&outp[b * 32 + e0 + e], v);
        }
    }
}

extern "C" void kernel_launch(void* const* d_in, const int* in_sizes, int n_in,
                              void* d_out, int out_size, void* d_ws, size_t ws_size,
                              hipStream_t stream) {
    const float* x     = (const float*)d_in[0];
    const float* gcn_w = (const float*)d_in[1];
    const float* wd    = (const float*)d_in[2];
    const float* bd    = (const float*)d_in[3];
    const float* t1_ws = (const float*)d_in[4];
    const float* t1_bs = (const float*)d_in[5];
    const float* t1_wm = (const float*)d_in[6];
    const float* t1_bm = (const float*)d_in[7];
    const float* t1_wl = (const float*)d_in[8];
    const float* t1_bl = (const float*)d_in[9];
    const float* t1_wo = (const float*)d_in[10];
    const float* t1_bo = (const float*)d_in[11];
    const float* t2_ws = (const float*)d_in[12];
    const float* t2_bs = (const float*)d_in[13];
    const float* t2_wm = (const float*)d_in[14];
    const float* t2_bm = (const float*)d_in[15];
    const float* t2_wl = (const float*)d_in[16];
    const float* t2_bl = (const float*)d_in[17];
    const float* t2_wo = (const float*)d_in[18];
    const float* t2_bo = (const float*)d_in[19];

    float* b0 = (float*)d_ws;                          // [16][64][4096]
    float* b1 = b0 + (size_t)BATCH * 64 * T_LEN;       // [16][64][4096]

    hipMemsetAsync(d_out, 0, (size_t)out_size * sizeof(float), stream);

    k_gcn<<<dim3(T_LEN / 16, BATCH), 256, 0, stream>>>(x, gcn_w, b0);

    k_mstcn<false><<<dim3(T_LEN / 64, BATCH), 256, 0, stream>>>(
        b0, t1_ws, t1_bs, t1_wm, t1_bm, t1_wl, t1_bl, t1_wo, t1_bo,
        b1, nullptr, nullptr, nullptr);

    k_mstcn<true><<<dim3(T_LEN / 64, BATCH), 256, 0, stream>>>(
        b1, t2_ws, t2_bs, t2_wm, t2_bm, t2_wl, t2_bl, t2_wo, t2_bo,
        nullptr, wd, bd, (float*)d_out);
}

// Round 7
// 371.445 us; speedup vs baseline: 1.2537x; 1.0483x over previous
//
#include <hip/hip_runtime.h>
#include <hip/hip_bf16.h>
#include <math.h>

#define T_LEN 4096
#define BATCH 16

// ---------------------------------------------------------------------------
// k_gcn: adapter + node projections + A_HAT propagation + relu + node-mean.
// Register-tiled: thread = 4d x 4t.  Bone weights (10 rows) in registers,
// palm weights from LDS (lane-varying b128).  One lane-varying x b128 per
// 16 FMAs (37% LDS duty vs 300% in the broadcast version).
// Output hp [B][64][T] channel-major.
// ---------------------------------------------------------------------------
__global__ __launch_bounds__(256) void k_gcn(
    const float* __restrict__ x,      // [B][T][218]
    const float* __restrict__ gcn_w,  // [18][64]
    float* __restrict__ hp)           // [B][64][T]
{
    __shared__ float xt[218 * 68];    // [c][64 t], stride 68
    __shared__ float wg[18 * 64];     // palm weights

    const int b   = blockIdx.y;
    const int t0  = blockIdx.x * 64;
    const int tid = threadIdx.x;

    // stage x transposed (scalar, coalesced on global side)
    const float* xb = x + ((long)b * T_LEN + t0) * 218;
    #pragma unroll 1
    for (int i = tid; i < 64 * 218; i += 256) {
        const int t = i / 218;
        const int c = i - 218 * t;
        xt[c * 68 + t] = xb[i];
    }
    for (int i = tid; i < 18 * 64; i += 256) wg[i] = gcn_w[i];
    __syncthreads();

    const int dg = tid >> 4;          // 16 groups x 4 d
    const int tt = tid & 15;          // 16 groups x 4 t
    const int d0 = dg * 4;
    const int tb = tt * 4;

    // bone weights (first 10 input channels) in registers
    float wr[10][4];
    #pragma unroll
    for (int c = 0; c < 10; ++c)
        *(float4*)wr[c] = *(const float4*)(gcn_w + c * 64 + d0);

    const float cP = 1.0f / 6.0f;
    const float cS = 0.23570226039551584f;   // 1/sqrt(18)
    const float c3 = 1.0f / 3.0f;
    const float cT = 0.4082482904638631f;    // 1/sqrt(6)
    const float cH = 0.5f;

    // palm projection h0 (18 channels, weights from LDS)
    float h0[4][4];
    #pragma unroll
    for (int di = 0; di < 4; ++di)
        #pragma unroll
        for (int ti = 0; ti < 4; ++ti) h0[di][ti] = 0.f;
    #pragma unroll 1
    for (int c = 0; c < 18; ++c) {
        float wv[4], xv[4];
        *(float4*)wv = *(const float4*)(&wg[c * 64 + d0]);
        *(float4*)xv = *(const float4*)(&xt[c * 68 + tb]);
        #pragma unroll
        for (int di = 0; di < 4; ++di)
            #pragma unroll
            for (int ti = 0; ti < 4; ++ti)
                h0[di][ti] = fmaf(wv[di], xv[ti], h0[di][ti]);
    }

    float pool[4][4], star[4][4];
    #pragma unroll
    for (int di = 0; di < 4; ++di)
        #pragma unroll
        for (int ti = 0; ti < 4; ++ti) { pool[di][ti] = 0.f; star[di][ti] = 0.f; }

    // fingers: nodes sequential, sliding chain state (register diet)
    #pragma unroll 1
    for (int f = 0; f < 5; ++f) {
        float hn[4][4], hprev[4][4], s12[4][4];
        #pragma unroll
        for (int n = 0; n < 4; ++n) {
            #pragma unroll
            for (int di = 0; di < 4; ++di)
                #pragma unroll
                for (int ti = 0; ti < 4; ++ti) hn[di][ti] = 0.f;
            const int cb = 18 + 10 * (4 * f + n);
            #pragma unroll
            for (int c = 0; c < 10; ++c) {
                float xv[4];
                *(float4*)xv = *(const float4*)(&xt[(cb + c) * 68 + tb]);
                #pragma unroll
                for (int di = 0; di < 4; ++di)
                    #pragma unroll
                    for (int ti = 0; ti < 4; ++ti)
                        hn[di][ti] = fmaf(wr[c][di], xv[ti], hn[di][ti]);
            }
            #pragma unroll
            for (int di = 0; di < 4; ++di)
                #pragma unroll
                for (int ti = 0; ti < 4; ++ti) {
                    const float h = hn[di][ti];
                    if (n == 0) {               // ha
                        star[di][ti] += h;
                        s12[di][ti] = h;
                        hprev[di][ti] = h;
                    } else if (n == 1) {        // h2: pa
                        const float pa = fmaf(cS, h0[di][ti], c3 * (s12[di][ti] + h));
                        pool[di][ti] += fmaxf(pa, 0.f);
                        s12[di][ti] += h;       // ha+h2
                        hprev[di][ti] = h;
                    } else if (n == 2) {        // h3: pb
                        const float pb = c3 * (s12[di][ti] + h);
                        pool[di][ti] += fmaxf(pb, 0.f);
                        s12[di][ti] = hprev[di][ti] + h;  // h2+h3 (reuse s12)
                        hprev[di][ti] = h;
                    } else {                    // he: pc, pe
                        const float pc = fmaf(cT, h, c3 * s12[di][ti]);
                        const float pe = fmaf(cT, hprev[di][ti], cH * h);
                        pool[di][ti] += fmaxf(pc, 0.f) + fmaxf(pe, 0.f);
                    }
                }
        }
    }

    float* hpb = hp + (long)b * 64 * T_LEN + t0 + tb;
    #pragma unroll
    for (int di = 0; di < 4; ++di) {
        float r[4];
        #pragma unroll
        for (int ti = 0; ti < 4; ++ti) {
            const float p0 = fmaf(cP, h0[di][ti], cS * star[di][ti]);
            r[ti] = (pool[di][ti] + fmaxf(p0, 0.f)) * (1.0f / 21.0f);
        }
        *(float4*)(hpb + (long)(d0 + di) * T_LEN) = make_float4(r[0], r[1], r[2], r[3]);
    }
}

// ---------------------------------------------------------------------------
// k_conv: three causal dilated convs + relu -> h (global).  No barriers
// after staging: waves retire when done.  thread = 4j x 8t, t-tile 128:
// conv_l = 10 ds_read_b128 per 288 FMAs (21% LDS duty).  Class->wave
// rotated per block (multiples of 4 keep waves class-uniform).
// ---------------------------------------------------------------------------
__global__ __launch_bounds__(256) void k_conv(
    const float* __restrict__ in,   // [B][64][T]
    const float* __restrict__ ws, const float* __restrict__ bs,
    const float* __restrict__ wm, const float* __restrict__ bm,
    const float* __restrict__ wl, const float* __restrict__ bl,
    float* __restrict__ h)          // [B][64][T]
{
    __shared__ float tile[64 * 164]; // [c][32 halo + 128 t + pad]

    const int b   = blockIdx.y;
    const int t0  = blockIdx.x * 128;
    const int tid = threadIdx.x;
    const int jl  = ((tid >> 4) + ((blockIdx.x & 3) << 2)) & 15;
    const int tt  = tid & 15;
    const int j0  = jl * 4;

    const float* inb = in + (long)b * 64 * T_LEN;
    #pragma unroll 1
    for (int i = tid; i < 64 * 40; i += 256) {
        const int c = i / 40;
        const int q = i - c * 40;
        const int t = t0 - 32 + q * 4;
        float4 v = make_float4(0.f, 0.f, 0.f, 0.f);
        if (t >= 0) v = *(const float4*)(inb + (long)c * T_LEN + t);
        *(float4*)(&tile[c * 164 + q * 4]) = v;
    }
    __syncthreads();

    float acc[4][8];

    if (jl < 4) {
        // conv_s: k=3, d=1 (concat 0..15)
        #pragma unroll
        for (int ji = 0; ji < 4; ++ji) {
            const float bv = bs[j0 + ji];
            #pragma unroll
            for (int i = 0; i < 8; ++i) acc[ji][i] = bv;
        }
        const float* wp = ws + j0;             // + c*16 + k*1024
        float w[3][4];
        #pragma unroll
        for (int k = 0; k < 3; ++k) *(float4*)w[k] = *(const float4*)(wp + k * 1024);
        #pragma unroll 1
        for (int c = 0; c < 64; ++c) {
            float win[12];                     // floats tt*8+28 .. +39
            const float* rb = &tile[c * 164 + tt * 8 + 28];
            #pragma unroll
            for (int m = 0; m < 3; ++m) *(float4*)(&win[4 * m]) = *(const float4*)(rb + 4 * m);
            const float* wn = wp + (c < 63 ? (c + 1) * 16 : 63 * 16);
            #pragma unroll
            for (int k = 0; k < 3; ++k) {
                #pragma unroll
                for (int i = 0; i < 8; ++i) {
                    const float v = win[2 + i + k];
                    #pragma unroll
                    for (int ji = 0; ji < 4; ++ji)
                        acc[ji][i] = fmaf(w[k][ji], v, acc[ji][i]);
                }
                *(float4*)w[k] = *(const float4*)(wn + k * 1024);
            }
        }
    } else if (jl < 8) {
        // conv_m: k=5, d=2 (concat 16..31)
        #pragma unroll
        for (int ji = 0; ji < 4; ++ji) {
            const float bv = bm[j0 - 16 + ji];
            #pragma unroll
            for (int i = 0; i < 8; ++i) acc[ji][i] = bv;
        }
        const float* wp = wm + (j0 - 16);
        float w[5][4];
        #pragma unroll
        for (int k = 0; k < 5; ++k) *(float4*)w[k] = *(const float4*)(wp + k * 1024);
        #pragma unroll 1
        for (int c = 0; c < 64; ++c) {
            float win[16];                     // floats tt*8+24 .. +39
            const float* rb = &tile[c * 164 + tt * 8 + 24];
            #pragma unroll
            for (int m = 0; m < 4; ++m) *(float4*)(&win[4 * m]) = *(const float4*)(rb + 4 * m);
            const float* wn = wp + (c < 63 ? (c + 1) * 16 : 63 * 16);
            #pragma unroll
            for (int k = 0; k < 5; ++k) {
                #pragma unroll
                for (int i = 0; i < 8; ++i) {
                    const float v = win[i + 2 * k];
                    #pragma unroll
                    for (int ji = 0; ji < 4; ++ji)
                        acc[ji][i] = fmaf(w[k][ji], v, acc[ji][i]);
                }
                *(float4*)w[k] = *(const float4*)(wn + k * 1024);
            }
        }
    } else {
        // conv_l: k=9, d=4 (concat 32..63)
        #pragma unroll
        for (int ji = 0; ji < 4; ++ji) {
            const float bv = bl[j0 - 32 + ji];
            #pragma unroll
            for (int i = 0; i < 8; ++i) acc[ji][i] = bv;
        }
        const float* wp = wl + (j0 - 32);      // + c*32 + k*2048
        float w[9][4];
        #pragma unroll
        for (int k = 0; k < 9; ++k) *(float4*)w[k] = *(const float4*)(wp + k * 2048);
        #pragma unroll 1
        for (int c = 0; c < 64; ++c) {
            float win[40];                     // floats tt*8 .. +39
            const float* rb = &tile[c * 164 + tt * 8];
            #pragma unroll
            for (int m = 0; m < 10; ++m) *(float4*)(&win[4 * m]) = *(const float4*)(rb + 4 * m);
            const float* wn = wp + (c < 63 ? (c + 1) * 32 : 63 * 32);
            #pragma unroll
            for (int k = 0; k < 9; ++k) {
                #pragma unroll
                for (int i = 0; i < 8; ++i) {
                    const float v = win[i + 4 * k];
                    #pragma unroll
                    for (int ji = 0; ji < 4; ++ji)
                        acc[ji][i] = fmaf(w[k][ji], v, acc[ji][i]);
                }
                *(float4*)w[k] = *(const float4*)(wn + k * 2048);
            }
        }
    }

    // relu + store, retire
    float* hb = h + (long)b * 64 * T_LEN + t0 + tt * 8;
    #pragma unroll
    for (int ji = 0; ji < 4; ++ji) {
        float* p = hb + (long)(j0 + ji) * T_LEN;
        *(float4*)(p)     = make_float4(fmaxf(acc[ji][0], 0.f), fmaxf(acc[ji][1], 0.f),
                                        fmaxf(acc[ji][2], 0.f), fmaxf(acc[ji][3], 0.f));
        *(float4*)(p + 4) = make_float4(fmaxf(acc[ji][4], 0.f), fmaxf(acc[ji][5], 0.f),
                                        fmaxf(acc[ji][6], 0.f), fmaxf(acc[ji][7], 0.f));
    }
}

// ---------------------------------------------------------------------------
// k_convout: 1x1 conv_out 64->64 (no relu), t-tile 128, thread 4d x 8t.
// h-tile and wo both in LDS; zero VMEM in the GEMM loop.
// FINAL fuses dense 64->32 + tanh + mean over T.
// ---------------------------------------------------------------------------
template <bool FINAL>
__global__ __launch_bounds__(256) void k_convout(
    const float* __restrict__ h,    // [B][64][T]
    const float* __restrict__ wo,   // [64][64]
    const float* __restrict__ bo,   // [64]
    float* __restrict__ out,        // [B][64][T]  (FINAL=false)
    const float* __restrict__ wd,   // [64][32]    (FINAL=true)
    const float* __restrict__ bd,   // [32]
    float* __restrict__ outp)       // [B][32]     (FINAL=true)
{
    __shared__ float hs[64 * 136];
    __shared__ float wos[64 * 64];

    const int b   = blockIdx.y;
    const int t0  = blockIdx.x * 128;
    const int tid = threadIdx.x;
    const int dg  = tid >> 4;
    const int tt  = tid & 15;
    const int d0  = dg * 4;

    const float* hbase = h + (long)b * 64 * T_LEN + t0;
    #pragma unroll 1
    for (int i = tid; i < 2048; i += 256) {
        const int row = i >> 5;
        const int q   = (i & 31) * 4;
        *(float4*)(&hs[row * 136 + q]) = *(const float4*)(hbase + (long)row * T_LEN + q);
    }
    #pragma unroll 1
    for (int i = tid; i < 1024; i += 256)
        *(float4*)(&wos[i * 4]) = *(const float4*)(wo + i * 4);
    __syncthreads();

    float o[4][8];
    {
        float bv[4];
        *(float4*)bv = *(const float4*)(bo + d0);
        #pragma unroll
        for (int di = 0; di < 4; ++di)
            #pragma unroll
            for (int i = 0; i < 8; ++i) o[di][i] = bv[di];
    }
    #pragma unroll 4
    for (int j = 0; j < 64; ++j) {
        float wv[4], hv[8];
        *(float4*)wv       = *(const float4*)(&wos[j * 64 + d0]);
        *(float4*)(&hv[0]) = *(const float4*)(&hs[j * 136 + tt * 8]);
        *(float4*)(&hv[4]) = *(const float4*)(&hs[j * 136 + tt * 8 + 4]);
        #pragma unroll
        for (int di = 0; di < 4; ++di)
            #pragma unroll
            for (int i = 0; i < 8; ++i)
                o[di][i] = fmaf(wv[di], hv[i], o[di][i]);
    }

    if (!FINAL) {
        float* ob = out + (long)b * 64 * T_LEN + t0 + tt * 8;
        #pragma unroll
        for (int di = 0; di < 4; ++di) {
            float* p = ob + (long)(d0 + di) * T_LEN;
            *(float4*)(p)     = make_float4(o[di][0], o[di][1], o[di][2], o[di][3]);
            *(float4*)(p + 4) = make_float4(o[di][4], o[di][5], o[di][6], o[di][7]);
        }
    } else {
        // fused head: dense 64->32 + tanh + mean over T (128 t = 2 per lane)
        __syncthreads();
        #pragma unroll
        for (int di = 0; di < 4; ++di) {
            float* p = &hs[(d0 + di) * 136 + tt * 8];
            *(float4*)(p)     = make_float4(o[di][0], o[di][1], o[di][2], o[di][3]);
            *(float4*)(p + 4) = make_float4(o[di][4], o[di][5], o[di][6], o[di][7]);
        }
        __syncthreads();

        const int lane = tid & 63;
        const int wv   = tid >> 6;
        const int e0   = wv * 8;
        float fa[8], fb[8];
        *(float4*)(&fa[0]) = *(const float4*)(bd + e0);
        *(float4*)(&fa[4]) = *(const float4*)(bd + e0 + 4);
        #pragma unroll
        for (int e = 0; e < 8; ++e) fb[e] = fa[e];

        #pragma unroll 4
        for (int d = 0; d < 64; ++d) {
            const float2 hv = *(const float2*)(&hs[d * 136 + lane * 2]);
            float wv8[8];
            *(float4*)(&wv8[0]) = *(const float4*)(wd + d * 32 + e0);
            *(float4*)(&wv8[4]) = *(const float4*)(wd + d * 32 + e0 + 4);
            #pragma unroll
            for (int e = 0; e < 8; ++e) {
                fa[e] = fmaf(wv8[e], hv.x, fa[e]);
                fb[e] = fmaf(wv8[e], hv.y, fb[e]);
            }
        }
        #pragma unroll
        for (int e = 0; e < 8; ++e) {
            float v = (tanhf(fa[e]) + tanhf(fb[e])) * (1.0f / (float)T_LEN);
            v += __shfl_down(v, 32);
            v += __shfl_down(v, 16);
            v += __shfl_down(v, 8);
            v += __shfl_down(v, 4);
            v += __shfl_down(v, 2);
            v += __shfl_down(v, 1);
            if (lane == 0) atomicAdd(&outp[b * 32 + e0 + e], v);
        }
    }
}

extern "C" void kernel_launch(void* const* d_in, const int* in_sizes, int n_in,
                              void* d_out, int out_size, void* d_ws, size_t ws_size,
                              hipStream_t stream) {
    const float* x     = (const float*)d_in[0];
    const float* gcn_w = (const float*)d_in[1];
    const float* wd    = (const float*)d_in[2];
    const float* bd    = (const float*)d_in[3];
    const float* t1_ws = (const float*)d_in[4];
    const float* t1_bs = (const float*)d_in[5];
    const float* t1_wm = (const float*)d_in[6];
    const float* t1_bm = (const float*)d_in[7];
    const float* t1_wl = (const float*)d_in[8];
    const float* t1_bl = (const float*)d_in[9];
    const float* t1_wo = (const float*)d_in[10];
    const float* t1_bo = (const float*)d_in[11];
    const float* t2_ws = (const float*)d_in[12];
    const float* t2_bs = (const float*)d_in[13];
    const float* t2_wm = (const float*)d_in[14];
    const float* t2_bm = (const float*)d_in[15];
    const float* t2_wl = (const float*)d_in[16];
    const float* t2_bl = (const float*)d_in[17];
    const float* t2_wo = (const float*)d_in[18];
    const float* t2_bo = (const float*)d_in[19];

    float* b0 = (float*)d_ws;                          // [16][64][4096]
    float* b1 = b0 + (size_t)BATCH * 64 * T_LEN;       // [16][64][4096]

    hipMemsetAsync(d_out, 0, (size_t)out_size * sizeof(float), stream);

    k_gcn<<<dim3(T_LEN / 64, BATCH), 256, 0, stream>>>(x, gcn_w, b0);

    k_conv<<<dim3(T_LEN / 128, BATCH), 256, 0, stream>>>(
        b0, t1_ws, t1_bs, t1_wm, t1_bm, t1_wl, t1_bl, b1);
    k_convout<false><<<dim3(T_LEN / 128, BATCH), 256, 0, stream>>>(
        b1, t1_wo, t1_bo, b0, nullptr, nullptr, nullptr);

    k_conv<<<dim3(T_LEN / 128, BATCH), 256, 0, stream>>>(
        b0, t2_ws, t2_bs, t2_wm, t2_bm, t2_wl, t2_bl, b1);
    k_convout<true><<<dim3(T_LEN / 128, BATCH), 256, 0, stream>>>(
        b1, t2_wo, t2_bo, nullptr, wd, bd, (float*)d_out);
}